// Round 1
// baseline (762.525 us; speedup 1.0000x reference)
//
#include <hip/hip_runtime.h>
#include <hip/hip_bf16.h>

// ---------------------------------------------------------------------------
// CPC_Net: 192 StageNet calls (each batch=16 seq of (3000,2)) + GRU + bilinear
// All fp32. Structure:
//   k0_prep : transpose wl, w3, wih, whh into ws
//   k1      : conv1 + conv2 + relu -> pooled(13) max/min + BN1 partial sums
//   k2      : BN1 affine + conv3 + relu -> pooled(13) + BN2 partial sums
//   k3      : BN2 affine + final linear -> feat[3072][100]
//   k4a/k4b : GRU over xc features -> hn[16][100]
//   k5      : bilinear scoring -> out (16,16,11)
// ---------------------------------------------------------------------------

#define NSEQ 3072
#define CNT1 94432.0f   // 16*2951*2
#define CNT2 5696.0f    // 16*178*2

// ---------------- k0: weight transposes ----------------
__global__ __launch_bounds__(256) void k0_prep(
    const float* __restrict__ wl, const float* __restrict__ w3,
    const float* __restrict__ wih, const float* __restrict__ whh,
    float* __restrict__ wlT, float* __restrict__ w3T,
    float* __restrict__ wihT, float* __restrict__ whhT)
{
    int i = blockIdx.x * 256 + threadIdx.x;
    if (i < 41600) { int h = i / 416, c = i - h * 416; wlT[c * 100 + h] = wl[i]; }
    if (i < 12800) { int co = i / 800, r = i - co * 800; int ci = r / 50, k = r - ci * 50;
                     w3T[(ci * 50 + k) * 16 + co] = w3[i]; }
    if (i < 30000) { int j = i / 100, c = i - j * 100;
                     wihT[c * 300 + j] = wih[i]; whhT[c * 300 + j] = whh[i]; }
}

// ---------------- k1: conv1 + conv2 + relu + pool + BN1 partials ----------------
// grid 3072 (one block per sequence), 256 threads
__global__ __launch_bounds__(256) void k1(
    const float* __restrict__ Xc, const float* __restrict__ Xp, const float* __restrict__ Xb,
    const float* __restrict__ w1, const float* __restrict__ b1,
    const float* __restrict__ w2, const float* __restrict__ b2,
    const float* __restrict__ g1,
    float* __restrict__ pooled1, float* __restrict__ bp1)
{
    const int s = blockIdx.x;
    const int g = s >> 4, b = s & 15;
    const float* x;
    if (g < 160)      { int p = g / 10, nb = g - p * 10; x = Xb + (size_t)((b * 16 + p) * 10 + nb) * 6000; }
    else if (g < 176) { int p = g - 160; x = Xc + (size_t)(b * 16 + p) * 6000; }
    else              { int p = g - 176; x = Xp + (size_t)(b * 16 + p) * 6000; }

    __shared__ float u[6000];     // conv1 output, [t][col]
    __shared__ float w2s[800];
    __shared__ float red[512];
    const int tid = threadIdx.x;

    for (int i = tid; i < 800; i += 256) w2s[i] = w2[i];
    float w100 = w1[0], w101 = w1[1], w110 = w1[2], w111 = w1[3];
    float b10 = b1[0], b11 = b1[1];
    for (int t = tid; t < 3000; t += 256) {
        float x0 = x[t * 2], x1 = x[t * 2 + 1];
        u[t * 2]     = fmaf(x1, w101, fmaf(x0, w100, b10));
        u[t * 2 + 1] = fmaf(x1, w111, fmaf(x0, w110, b11));
    }
    __syncthreads();

    const int pair = tid & 31, ch = pair >> 1, col = pair & 1, w8 = tid >> 5;
    float wk[50];
    #pragma unroll
    for (int k = 0; k < 50; ++k) wk[k] = w2s[ch * 50 + k];
    const float bias = b2[ch];
    const bool useMax = (g1[ch] >= 0.0f);

    float lsum = 0.0f, lsq = 0.0f;
    #pragma unroll 1
    for (int w = w8; w < 227; w += 8) {
        const int t0 = w * 13;
        float acc[13];
        #pragma unroll
        for (int j = 0; j < 13; ++j) acc[j] = bias;
        #pragma unroll
        for (int tk = 0; tk < 62; ++tk) {
            float uv = u[(t0 + tk) * 2 + col];
            const int jlo = (tk > 49) ? (tk - 49) : 0;
            const int jhi = (tk < 12) ? tk : 12;
            #pragma unroll
            for (int j = 0; j < 13; ++j)
                if (j >= jlo && j <= jhi) acc[j] = fmaf(uv, wk[tk - j], acc[j]);
        }
        float sel = useMax ? -1e30f : 1e30f;
        #pragma unroll
        for (int j = 0; j < 13; ++j) {
            float r = fmaxf(acc[j], 0.0f);
            lsum += r; lsq = fmaf(r, r, lsq);
            sel = useMax ? fmaxf(sel, r) : fminf(sel, r);
        }
        pooled1[(size_t)s * 7264 + (size_t)w * 32 + pair] = sel;
    }

    red[tid] = lsum;
    __syncthreads();
    float partial_sq = lsq;           // stash while red holds sums
    if (tid < 16) {
        float a = 0.0f;
        for (int t = 0; t < 16; ++t) { int idx = (t >> 1) * 32 + tid * 2 + (t & 1); a += red[idx]; }
        bp1[(s * 16 + tid) * 2 + 0] = a;
    }
    __syncthreads();
    red[tid] = partial_sq;
    __syncthreads();
    if (tid < 16) {
        float q = 0.0f;
        for (int t = 0; t < 16; ++t) { int idx = (t >> 1) * 32 + tid * 2 + (t & 1); q += red[idx]; }
        bp1[(s * 16 + tid) * 2 + 1] = q;
    }
}

// ---------------- k2: BN1 affine + conv3 + relu + pool + BN2 partials ----------------
// grid 3072, 512 threads
__global__ __launch_bounds__(512) void k2(
    const float* __restrict__ pooled1, const float* __restrict__ bp1,
    const float* __restrict__ g1, const float* __restrict__ be1,
    const float* __restrict__ w3T, const float* __restrict__ b3,
    const float* __restrict__ g2,
    float* __restrict__ pooled2, float* __restrict__ bp2)
{
    const int s = blockIdx.x, g = s >> 4;
    __shared__ float in2[7424];   // [col][ci][232], zero padded past w=226
    __shared__ float w3b[800];    // [k][co] for current ci
    __shared__ float sc1[16], sh1[16];
    __shared__ float red[1024];
    const int tid = threadIdx.x;

    if (tid < 16) {
        float sum = 0.0f, sq = 0.0f;
        for (int sb = 0; sb < 16; ++sb) {
            const float* pp = &bp1[((g * 16 + sb) * 16 + tid) * 2];
            sum += pp[0]; sq += pp[1];
        }
        float m = sum * (1.0f / CNT1);
        float v = sq * (1.0f / CNT1) - m * m;
        float scv = g1[tid] * rsqrtf(v + 1e-5f);
        sc1[tid] = scv; sh1[tid] = be1[tid] - m * scv;
    }
    for (int i = tid; i < 7424; i += 512) in2[i] = 0.0f;
    __syncthreads();
    for (int idx = tid; idx < 7264; idx += 512) {
        int w = idx >> 5, pr = idx & 31, ch = pr >> 1, cl = pr & 1;
        in2[(cl * 16 + ch) * 232 + w] = fmaf(pooled1[(size_t)s * 7264 + idx], sc1[ch], sh1[ch]);
    }

    const int pair = tid & 31, co = pair >> 1, col = pair & 1, wslot = tid >> 5;
    const bool active = (wslot < 14);
    const int t0 = wslot * 13;
    float acc[13];
    const float bias = b3[co];
    #pragma unroll
    for (int j = 0; j < 13; ++j) acc[j] = bias;

    for (int ci = 0; ci < 16; ++ci) {
        __syncthreads();   // also covers in2 writes for ci==0
        for (int i = tid; i < 800; i += 512) w3b[i] = w3T[ci * 800 + i];
        __syncthreads();
        if (active) {
            float wk[50];
            #pragma unroll
            for (int k = 0; k < 50; ++k) wk[k] = w3b[k * 16 + co];
            const float* ip = &in2[(col * 16 + ci) * 232 + t0];
            #pragma unroll
            for (int tk = 0; tk < 62; ++tk) {
                float uv = ip[tk];
                const int jlo = (tk > 49) ? (tk - 49) : 0;
                const int jhi = (tk < 12) ? tk : 12;
                #pragma unroll
                for (int j = 0; j < 13; ++j)
                    if (j >= jlo && j <= jhi) acc[j] = fmaf(uv, wk[tk - j], acc[j]);
            }
        }
    }

    float lsum = 0.0f, lsq = 0.0f;
    const bool useMax2 = (g2[co] >= 0.0f);
    float sel = useMax2 ? -1e30f : 1e30f;
    if (active) {
        const int base = wslot * 13;
        #pragma unroll
        for (int j = 0; j < 13; ++j) {
            if (base + j < 178) {
                float r = fmaxf(acc[j], 0.0f);
                lsum += r; lsq = fmaf(r, r, lsq);
                sel = useMax2 ? fmaxf(sel, r) : fminf(sel, r);
            }
        }
        if (wslot < 13) pooled2[(size_t)s * 416 + co * 26 + wslot * 2 + col] = sel;
    }
    red[tid] = lsum; red[512 + tid] = lsq;
    __syncthreads();
    if (tid < 16) {
        float a = 0.0f, q = 0.0f;
        for (int t = 0; t < 32; ++t) {
            int idx = (t >> 1) * 32 + tid * 2 + (t & 1);
            a += red[idx]; q += red[512 + idx];
        }
        bp2[(s * 16 + tid) * 2 + 0] = a;
        bp2[(s * 16 + tid) * 2 + 1] = q;
    }
}

// ---------------- k3: BN2 affine + linear ----------------
// grid 3072, 128 threads
__global__ __launch_bounds__(128) void k3(
    const float* __restrict__ bp2, const float* __restrict__ g2, const float* __restrict__ be2,
    const float* __restrict__ pooled2, const float* __restrict__ wlT,
    const float* __restrict__ bl, float* __restrict__ feat)
{
    const int s = blockIdx.x, g = s >> 4;
    const int tid = threadIdx.x;
    __shared__ float sc[16], sh[16], z[416];
    if (tid < 16) {
        float sum = 0.0f, sq = 0.0f;
        for (int sb = 0; sb < 16; ++sb) {
            const float* pp = &bp2[((g * 16 + sb) * 16 + tid) * 2];
            sum += pp[0]; sq += pp[1];
        }
        float m = sum * (1.0f / CNT2);
        float v = sq * (1.0f / CNT2) - m * m;
        float scv = g2[tid] * rsqrtf(v + 1e-5f);
        sc[tid] = scv; sh[tid] = be2[tid] - m * scv;
    }
    __syncthreads();
    for (int i = tid; i < 416; i += 128) {
        int co = i / 26;
        z[i] = fmaf(pooled2[(size_t)s * 416 + i], sc[co], sh[co]);
    }
    __syncthreads();
    for (int h = tid; h < 100; h += 128) {
        float acc = bl[h];
        for (int i = 0; i < 416; ++i) acc = fmaf(wlT[i * 100 + h], z[i], acc);
        feat[(size_t)s * 100 + h] = acc;
    }
}

// ---------------- k4a: GRU input gates (all steps, parallel) ----------------
// grid 256 (b,p), 128 threads
__global__ __launch_bounds__(128) void k4a(
    const float* __restrict__ feat, const float* __restrict__ wihT,
    const float* __restrict__ bih, float* __restrict__ gi)
{
    const int b = blockIdx.x >> 4, p = blockIdx.x & 15;
    const int tid = threadIdx.x;
    __shared__ float xr[100];
    if (tid < 100) xr[tid] = feat[(size_t)((160 + p) * 16 + b) * 100 + tid];
    __syncthreads();
    for (int j = tid; j < 300; j += 128) {
        float acc = bih[j];
        for (int i = 0; i < 100; ++i) acc = fmaf(xr[i], wihT[i * 300 + j], acc);
        gi[(size_t)(b * 16 + p) * 300 + j] = acc;
    }
}

// ---------------- k4b: GRU recurrence ----------------
// grid 16 (b), 320 threads
__global__ __launch_bounds__(320) void k4b(
    const float* __restrict__ gi, const float* __restrict__ whhT,
    const float* __restrict__ bhh, float* __restrict__ hn)
{
    const int b = blockIdx.x;
    const int tid = threadIdx.x;
    __shared__ float h[100], ga[300], gb[300];
    if (tid < 100) h[tid] = 0.0f;
    __syncthreads();
    for (int p = 0; p < 16; ++p) {
        if (tid < 300) {
            float acc = bhh[tid];
            for (int i = 0; i < 100; ++i) acc = fmaf(h[i], whhT[i * 300 + tid], acc);
            gb[tid] = acc;
            ga[tid] = gi[(size_t)(b * 16 + p) * 300 + tid];
        }
        __syncthreads();
        if (tid < 100) {
            float r  = 1.0f / (1.0f + expf(-(ga[tid] + gb[tid])));
            float zz = 1.0f / (1.0f + expf(-(ga[100 + tid] + gb[100 + tid])));
            float n  = tanhf(ga[200 + tid] + r * gb[200 + tid]);
            h[tid] = (1.0f - zz) * n + zz * h[tid];
        }
        __syncthreads();
    }
    if (tid < 100) hn[b * 100 + tid] = h[tid];
}

// ---------------- k5: bilinear scoring ----------------
// grid 256 (b,p), 128 threads
__global__ __launch_bounds__(128) void k5(
    const float* __restrict__ hn, const float* __restrict__ bw,
    const float* __restrict__ feat, float* __restrict__ out)
{
    const int b = blockIdx.x >> 4, p = blockIdx.x & 15;
    const int tid = threadIdx.x;
    __shared__ float hs[100], ts[100];
    if (tid < 100) hs[tid] = hn[b * 100 + tid];
    __syncthreads();
    if (tid < 100) {
        float acc = 0.0f;
        for (int hh = 0; hh < 100; ++hh)
            acc = fmaf(hs[hh], bw[(size_t)(p * 100 + hh) * 100 + tid], acc);
        ts[tid] = acc;
    }
    __syncthreads();
    if (tid < 11) {
        const float* cr = (tid == 0)
            ? &feat[(size_t)((176 + p) * 16 + b) * 100]
            : &feat[(size_t)((p * 10 + tid - 1) * 16 + b) * 100];
        float acc = 0.0f;
        for (int hh = 0; hh < 100; ++hh) acc = fmaf(ts[hh], cr[hh], acc);
        out[(b * 16 + p) * 11 + tid] = acc;
    }
}

// ---------------------------------------------------------------------------
extern "C" void kernel_launch(void* const* d_in, const int* in_sizes, int n_in,
                              void* d_out, int out_size, void* d_ws, size_t ws_size,
                              hipStream_t stream) {
    (void)in_sizes; (void)n_in; (void)out_size; (void)ws_size;
    const float* Xc  = (const float*)d_in[0];
    const float* Xp  = (const float*)d_in[1];
    const float* Xb  = (const float*)d_in[2];
    const float* w1  = (const float*)d_in[3];
    const float* b1  = (const float*)d_in[4];
    const float* w2  = (const float*)d_in[5];
    const float* b2  = (const float*)d_in[6];
    const float* g1  = (const float*)d_in[7];
    const float* be1 = (const float*)d_in[8];
    const float* w3  = (const float*)d_in[9];
    const float* b3  = (const float*)d_in[10];
    const float* g2  = (const float*)d_in[11];
    const float* be2 = (const float*)d_in[12];
    const float* wl  = (const float*)d_in[13];
    const float* bl  = (const float*)d_in[14];
    const float* wih = (const float*)d_in[15];
    const float* whh = (const float*)d_in[16];
    const float* bih = (const float*)d_in[17];
    const float* bhh = (const float*)d_in[18];
    const float* bw  = (const float*)d_in[19];

    float* ws      = (float*)d_ws;
    float* bp1     = ws;                 // 98304
    float* bp2     = ws + 98304;         // 98304
    float* wlT     = ws + 196608;        // 41600
    float* w3T     = ws + 238208;        // 12800
    float* wihT    = ws + 251008;        // 30000
    float* whhT    = ws + 281008;        // 30000
    float* gi      = ws + 311008;        // 76800
    float* hn      = ws + 387808;        // 1600
    float* feat    = ws + 389408;        // 307200
    float* pooled2 = ws + 696608;        // 1277952
    float* pooled1 = ws + 1974560;       // 22302720  (total ~97.1 MB)

    k0_prep<<<163, 256, 0, stream>>>(wl, w3, wih, whh, wlT, w3T, wihT, whhT);
    k1<<<NSEQ, 256, 0, stream>>>(Xc, Xp, Xb, w1, b1, w2, b2, g1, pooled1, bp1);
    k2<<<NSEQ, 512, 0, stream>>>(pooled1, bp1, g1, be1, w3T, b3, g2, pooled2, bp2);
    k3<<<NSEQ, 128, 0, stream>>>(bp2, g2, be2, pooled2, wlT, bl, feat);
    k4a<<<256, 128, 0, stream>>>(feat, wihT, bih, gi);
    k4b<<<16, 320, 0, stream>>>(gi, whhT, bhh, hn);
    k5<<<256, 128, 0, stream>>>(hn, bw, feat, (float*)d_out);
}